// Round 1
// baseline (371.798 us; speedup 1.0000x reference)
//
#include <hip/hip_runtime.h>
#include <hip/hip_bf16.h>

using f32x4  = __attribute__((ext_vector_type(4))) float;
using bf16x8 = __attribute__((ext_vector_type(8))) short;
using u32x4  = __attribute__((ext_vector_type(4))) unsigned int;

__device__ __forceinline__ float bf2f(short s) {
    unsigned u = ((unsigned)(unsigned short)s) << 16;
    return __builtin_bit_cast(float, u);
}
__device__ __forceinline__ unsigned short f2b(float f) {
    unsigned u = __builtin_bit_cast(unsigned, f);
    unsigned r = u + 0x7FFFu + ((u >> 16) & 1u);   // RNE
    return (unsigned short)(r >> 16);
}

// ---------------- weight convert: Wqkv (768x256) + Wproj (256x256) -> bf16 ----------------
__global__ void k_wconv(const float* __restrict__ wq, const float* __restrict__ wp,
                        unsigned short* __restrict__ out) {
    int i = blockIdx.x * 256 + threadIdx.x;       // grid covers exactly 262144
    float v = (i < 196608) ? wq[i] : wp[i - 196608];
    out[i] = f2b(v);
}

// ---------------- fused window-gather + qkv GEMM + attention ----------------
// block: 14 windows (126 rows, padded to 128), 256 threads (4 waves)
__global__ __launch_bounds__(256) void k_winattn(
    const float* __restrict__ x,
    const unsigned short* __restrict__ wqkv,   // bf16 [768][256]  ([N][K])
    unsigned short* __restrict__ aout)         // bf16 [147456][256], x-row order
{
    constexpr int LDA = 264, LDW = 264, LQ = 72;
    __shared__ unsigned short As[128 * LDA];   // 67584 B
    __shared__ unsigned short Ws[64 * LDW];    // 33792 B (reused as fp32 score scratch)
    __shared__ unsigned short Qb[3][128 * LQ]; // 55296 B
    __shared__ int rowmap[128];

    const int tid = threadIdx.x;
    const int wbase = blockIdx.x * 14;

    if (tid < 128) {
        int gr = -1;
        if (tid < 126) {
            int wi = tid / 9;
            int t  = tid - wi * 9;
            int w  = wbase + wi;
            if (w < 16384) {
                int b = w >> 10, rem = w & 1023;
                int wh = rem >> 5, ww = rem & 31;
                int r = t / 3, c = t - r * 3;
                gr = b * 9216 + (wh * 3 + r) * 96 + (ww * 3 + c);
            }
        }
        rowmap[tid] = gr;
    }
    __syncthreads();

    int nv = 16384 - wbase; nv = (nv > 14 ? 14 : nv) * 9;   // valid rows in this block

    // stage x rows -> As (bf16), zeros for pad rows
    for (int idx = tid; idx < 128 * 32; idx += 256) {
        int row = idx >> 5, g = idx & 31;
        int gr = rowmap[row];
        bf16x8 v;
        if (gr >= 0) {
            const f32x4* p = (const f32x4*)(x + (size_t)gr * 256 + g * 8);
            f32x4 f0 = p[0], f1 = p[1];
#pragma unroll
            for (int j = 0; j < 4; ++j) {
                v[j]     = (short)f2b(f0[j]);
                v[4 + j] = (short)f2b(f1[j]);
            }
        } else {
#pragma unroll
            for (int j = 0; j < 8; ++j) v[j] = 0;
        }
        *(bf16x8*)&As[row * LDA + g * 8] = v;
    }

    const int wv = tid >> 6, ln = tid & 63;
    const int lr = ln & 15, lk = ln >> 4;
    float* sc = (float*)Ws;                    // [2][128][12] fp32 scratch (12288 B)

    for (int h = 0; h < 4; ++h) {
        for (int part = 0; part < 3; ++part) {
            __syncthreads();                   // Ws free (prev GEMM reads / attn scratch done)
            const int j0 = part * 256 + h * 64;
            for (int idx = tid; idx < 64 * 32; idx += 256) {
                int rr = idx >> 5, g = idx & 31;
                *(bf16x8*)&Ws[rr * LDW + g * 8] =
                    *(const bf16x8*)(wqkv + (size_t)(j0 + rr) * 256 + g * 8);
            }
            __syncthreads();

            f32x4 acc[2][4];
#pragma unroll
            for (int mi = 0; mi < 2; ++mi)
#pragma unroll
                for (int ni = 0; ni < 4; ++ni) {
                    f32x4 z = {0.f, 0.f, 0.f, 0.f};
                    acc[mi][ni] = z;
                }
#pragma unroll
            for (int kk = 0; kk < 8; ++kk) {
                const int k0 = kk * 32 + lk * 8;
                bf16x8 a0 = *(const bf16x8*)&As[(wv * 32 + lr) * LDA + k0];
                bf16x8 a1 = *(const bf16x8*)&As[(wv * 32 + 16 + lr) * LDA + k0];
#pragma unroll
                for (int ni = 0; ni < 4; ++ni) {
                    bf16x8 b = *(const bf16x8*)&Ws[(ni * 16 + lr) * LDW + k0];
                    acc[0][ni] = __builtin_amdgcn_mfma_f32_16x16x32_bf16(a0, b, acc[0][ni], 0, 0, 0);
                    acc[1][ni] = __builtin_amdgcn_mfma_f32_16x16x32_bf16(a1, b, acc[1][ni], 0, 0, 0);
                }
            }
            // C layout (m89-verified): col = lane&15, row = (lane>>4)*4 + reg
            unsigned short* qp = Qb[part];
#pragma unroll
            for (int mi = 0; mi < 2; ++mi)
#pragma unroll
                for (int ni = 0; ni < 4; ++ni)
#pragma unroll
                    for (int r = 0; r < 4; ++r) {
                        int row = wv * 32 + mi * 16 + lk * 4 + r;
                        qp[row * LQ + ni * 16 + lr] = f2b(acc[mi][ni][r]);
                    }
        }
        __syncthreads();   // q,k,v of head h ready in Qb; Ws free for scores

        // ---- attention, head h: thread = (row, d-half) ----
        {
            const int row = tid & 127, dh = tid >> 7;
            const bool act = row < nv;
            const int w9 = (row / 9) * 9;
            if (act) {
                float qv[32];
                const int qbase = row * LQ + dh * 32;
#pragma unroll
                for (int g = 0; g < 4; ++g) {
                    bf16x8 v = *(const bf16x8*)&Qb[0][qbase + g * 8];
#pragma unroll
                    for (int j = 0; j < 8; ++j) qv[g * 8 + j] = bf2f(v[j]);
                }
#pragma unroll
                for (int kk = 0; kk < 9; ++kk) {
                    const int kbase = (w9 + kk) * LQ + dh * 32;
                    float s = 0.f;
#pragma unroll
                    for (int g = 0; g < 4; ++g) {
                        bf16x8 v = *(const bf16x8*)&Qb[1][kbase + g * 8];
#pragma unroll
                        for (int j = 0; j < 8; ++j) s += qv[g * 8 + j] * bf2f(v[j]);
                    }
                    sc[(dh * 128 + row) * 12 + kk] = s;
                }
            }
            __syncthreads();
            if (tid < 128 && tid < nv) {
                float s[9], m = -1e30f;
#pragma unroll
                for (int kk = 0; kk < 9; ++kk) {
                    s[kk] = (sc[tid * 12 + kk] + sc[(128 + tid) * 12 + kk]) * 0.125f;
                    m = fmaxf(m, s[kk]);
                }
                float sum = 0.f;
#pragma unroll
                for (int kk = 0; kk < 9; ++kk) { s[kk] = __expf(s[kk] - m); sum += s[kk]; }
                float inv = 1.f / sum;
#pragma unroll
                for (int kk = 0; kk < 9; ++kk) sc[tid * 12 + kk] = s[kk] * inv;
            }
            __syncthreads();
            if (act) {
                float p[9];
#pragma unroll
                for (int kk = 0; kk < 9; ++kk) p[kk] = sc[row * 12 + kk];
                float o[32];
#pragma unroll
                for (int d = 0; d < 32; ++d) o[d] = 0.f;
#pragma unroll
                for (int kk = 0; kk < 9; ++kk) {
                    const int vbase = (w9 + kk) * LQ + dh * 32;
#pragma unroll
                    for (int g = 0; g < 4; ++g) {
                        bf16x8 v = *(const bf16x8*)&Qb[2][vbase + g * 8];
#pragma unroll
                        for (int j = 0; j < 8; ++j) o[g * 8 + j] += p[kk] * bf2f(v[j]);
                    }
                }
                const int grow = rowmap[row];
#pragma unroll
                for (int q = 0; q < 4; ++q) {
                    u32x4 u;
#pragma unroll
                    for (int e = 0; e < 4; ++e) {
                        int i0 = q * 8 + e * 2;
                        u[e] = (unsigned)f2b(o[i0]) | ((unsigned)f2b(o[i0 + 1]) << 16);
                    }
                    *(u32x4*)(aout + (size_t)grow * 256 + h * 64 + dh * 32 + q * 8) = u;
                }
            }
        }
        // next iteration's leading __syncthreads() protects Ws/Qb reuse
    }
}

// ---------------- proj GEMM: [147456][256] bf16 @ Wproj^T -> fp32 out ----------------
__global__ __launch_bounds__(256) void k_proj(
    const unsigned short* __restrict__ ain,    // bf16 [147456][256]
    const unsigned short* __restrict__ wproj,  // bf16 [256][256] ([N][K])
    float* __restrict__ out)
{
    constexpr int LDA = 264, LDW = 264;
    __shared__ unsigned short As[128 * LDA];
    __shared__ unsigned short Ws[64 * LDW];
    const int tid = threadIdx.x;
    const size_t row0 = (size_t)blockIdx.x * 128;

    for (int idx = tid; idx < 128 * 32; idx += 256) {
        int row = idx >> 5, g = idx & 31;
        *(bf16x8*)&As[row * LDA + g * 8] =
            *(const bf16x8*)(ain + (row0 + row) * 256 + g * 8);
    }

    const int wv = tid >> 6, ln = tid & 63;
    const int lr = ln & 15, lk = ln >> 4;

    for (int nc = 0; nc < 4; ++nc) {
        __syncthreads();
        const int j0 = nc * 64;
        for (int idx = tid; idx < 64 * 32; idx += 256) {
            int rr = idx >> 5, g = idx & 31;
            *(bf16x8*)&Ws[rr * LDW + g * 8] =
                *(const bf16x8*)(wproj + (size_t)(j0 + rr) * 256 + g * 8);
        }
        __syncthreads();

        f32x4 acc[2][4];
#pragma unroll
        for (int mi = 0; mi < 2; ++mi)
#pragma unroll
            for (int ni = 0; ni < 4; ++ni) {
                f32x4 z = {0.f, 0.f, 0.f, 0.f};
                acc[mi][ni] = z;
            }
#pragma unroll
        for (int kk = 0; kk < 8; ++kk) {
            const int k0 = kk * 32 + lk * 8;
            bf16x8 a0 = *(const bf16x8*)&As[(wv * 32 + lr) * LDA + k0];
            bf16x8 a1 = *(const bf16x8*)&As[(wv * 32 + 16 + lr) * LDA + k0];
#pragma unroll
            for (int ni = 0; ni < 4; ++ni) {
                bf16x8 b = *(const bf16x8*)&Ws[(ni * 16 + lr) * LDW + k0];
                acc[0][ni] = __builtin_amdgcn_mfma_f32_16x16x32_bf16(a0, b, acc[0][ni], 0, 0, 0);
                acc[1][ni] = __builtin_amdgcn_mfma_f32_16x16x32_bf16(a1, b, acc[1][ni], 0, 0, 0);
            }
        }
#pragma unroll
        for (int mi = 0; mi < 2; ++mi)
#pragma unroll
            for (int ni = 0; ni < 4; ++ni)
#pragma unroll
                for (int r = 0; r < 4; ++r) {
                    int row = wv * 32 + mi * 16 + lk * 4 + r;
                    out[(row0 + row) * 256 + j0 + ni * 16 + lr] = acc[mi][ni][r];
                }
    }
}

extern "C" void kernel_launch(void* const* d_in, const int* in_sizes, int n_in,
                              void* d_out, int out_size, void* d_ws, size_t ws_size,
                              hipStream_t stream) {
    const float* x  = (const float*)d_in[0];
    const float* wq = (const float*)d_in[1];
    const float* wp = (const float*)d_in[2];
    unsigned short* wsb     = (unsigned short*)d_ws;
    unsigned short* wqkv_b  = wsb;                // 196608 elems
    unsigned short* wproj_b = wsb + 196608;       //  65536 elems
    unsigned short* aout    = wsb + 262144;       // 147456*256 bf16
    float* out = (float*)d_out;

    k_wconv  <<<1024, 256, 0, stream>>>(wq, wp, wsb);
    k_winattn<<<1171, 256, 0, stream>>>(x, wqkv_b, aout);
    k_proj   <<<1152, 256, 0, stream>>>(aout, wproj_b, out);
}